// Round 1
// baseline (3230.749 us; speedup 1.0000x reference)
//
#include <hip/hip_runtime.h>
#include <math.h>

#ifndef __has_builtin
#define __has_builtin(x) 0
#endif

// --- fast native transcendentals (base-2 domain) ---
__device__ __forceinline__ float fexp2(float x) {
#if __has_builtin(__builtin_amdgcn_exp2f)
  return __builtin_amdgcn_exp2f(x);
#else
  return exp2f(x);
#endif
}
__device__ __forceinline__ float flog2(float x) {
#if __has_builtin(__builtin_amdgcn_logf)
  return __builtin_amdgcn_logf(x);
#else
  return log2f(x);
#endif
}
__device__ __forceinline__ float fsqrt_(float x) {
#if __has_builtin(__builtin_amdgcn_sqrtf)
  return __builtin_amdgcn_sqrtf(x);
#else
  return sqrtf(x);
#endif
}

constexpr int   NP    = 6144;
constexpr float LOG2E = 1.44269504088896340736f;
constexpr float EPS_F = 0.01f;
constexpr float KKc   = LOG2E / EPS_F;              // log2(e)/eps
constexpr float LBc   = -8.72323127482750f;          // log(1/6144)
constexpr float HBc   = LBc * LOG2E;                 // log-weight in base-2
constexpr float NEL2c = -EPS_F * 0.693147180559945f; // -eps*ln(2)

constexpr int TILE = 512;          // Q points staged per LDS tile
constexpr int NT   = NP / TILE;    // 12 tiles
constexpr int RPW  = 8;            // rows per wave
constexpr int RPB  = 32;           // rows per block (4 waves)
constexpr int BPS  = NP / RPB;     // 192 blocks per subproblem

// Precompute packed coords (x,y,z,|p|^2) and zero the 4 state arrays.
__global__ __launch_bounds__(256) void init_kernel(
    const float* __restrict__ x, const float* __restrict__ y,
    float4* __restrict__ X4, float4* __restrict__ Y4,
    float* __restrict__ st)
{
  int i = blockIdx.x * 256 + threadIdx.x;
  if (i < NP) {
    float a0 = x[3*i], a1 = x[3*i+1], a2 = x[3*i+2];
    X4[i] = make_float4(a0, a1, a2, fmaf(a0, a0, fmaf(a1, a1, a2*a2)));
    float b0 = y[3*i], b1 = y[3*i+1], b2 = y[3*i+2];
    Y4[i] = make_float4(b0, b1, b2, fmaf(b0, b0, fmaf(b1, b1, b2*b2)));
    st[i] = 0.f; st[i + NP] = 0.f; st[i + 2*NP] = 0.f; st[i + 3*NP] = 0.f;
  }
}

// One Sinkhorn step: 4 fused softmin passes (ft, gt, p_x, p_y).
// sub 0: out_f  = softmin rows of C_xy  (P=x, Q=y, h from g)
// sub 1: out_g  = softmin cols of C_xy  (P=y, Q=x, h from f)
// sub 2: out_px = softmin rows of C_xx  (h from px)
// sub 3: out_py = softmin rows of C_yy  (h from py)
// If avg: out = 0.5*(old + softmin) else out = softmin.
__global__ __launch_bounds__(256, 4) void softmin_pass(
    const float4* __restrict__ X4, const float4* __restrict__ Y4,
    const float* __restrict__ f_in,  const float* __restrict__ g_in,
    const float* __restrict__ px_in, const float* __restrict__ py_in,
    float* __restrict__ f_out,  float* __restrict__ g_out,
    float* __restrict__ px_out, float* __restrict__ py_out,
    int avg)
{
  __shared__ float4 sQ[TILE];
  __shared__ float  sH[TILE];

  const int bid   = blockIdx.x;
  const int sub   = bid / BPS;
  const int row0  = (bid - sub * BPS) * RPB;
  const int tid   = threadIdx.x;
  const int lane  = tid & 63;
  const int wave  = tid >> 6;
  const int wrow0 = row0 + wave * RPW;

  const float4* P4;  const float4* Q4;
  const float* hsrc; const float* oldp; float* outp;
  if (sub == 0)      { P4 = X4; Q4 = Y4; hsrc = g_in;  oldp = f_in;  outp = f_out;  }
  else if (sub == 1) { P4 = Y4; Q4 = X4; hsrc = f_in;  oldp = g_in;  outp = g_out;  }
  else if (sub == 2) { P4 = X4; Q4 = X4; hsrc = px_in; oldp = px_in; outp = px_out; }
  else               { P4 = Y4; Q4 = Y4; hsrc = py_in; oldp = py_in; outp = py_out; }

  float pxr[RPW], pyr[RPW], pzr[RPW], pwr[RPW];
  float mr[RPW], sr[RPW];
#pragma unroll
  for (int r = 0; r < RPW; ++r) {
    float4 p = P4[wrow0 + r];
    pxr[r] = p.x; pyr[r] = p.y; pzr[r] = p.z; pwr[r] = p.w;
    mr[r] = -INFINITY; sr[r] = 0.f;
  }

  for (int t = 0; t < NT; ++t) {
    __syncthreads();
#pragma unroll
    for (int v = tid; v < TILE; v += 256) {
      sQ[v] = Q4[t * TILE + v];
      sH[v] = fmaf(KKc, hsrc[t * TILE + v], HBc);  // (logw + state/eps)*log2e
    }
    __syncthreads();
#pragma unroll 2
    for (int k = lane; k < TILE; k += 64) {
      const float4 q  = sQ[k];
      const float  hh = sH[k];
#pragma unroll
      for (int r = 0; r < RPW; ++r) {
        float dot = fmaf(pxr[r], q.x, fmaf(pyr[r], q.y, pzr[r] * q.z));
        float d2  = fmaf(-2.f, dot, pwr[r] + q.w);
        float c   = fsqrt_(fmaxf(d2, 0.f) + 1e-12f);
        float u   = fmaf(-KKc, c, hh);          // base-2 exponent
        // defer-max: rescale only when new value exceeds running max by >40
        if (u > mr[r] + 40.f) { sr[r] *= fexp2(mr[r] - u); mr[r] = u; }
        sr[r] += fexp2(u - mr[r]);
      }
    }
  }

  // combine per-lane partial (m, s) LSE states across the wave
#pragma unroll
  for (int r = 0; r < RPW; ++r) {
    float m = mr[r], s = sr[r];
#pragma unroll
    for (int off = 32; off; off >>= 1) {
      float mo = __shfl_xor(m, off);
      float so = __shfl_xor(s, off);
      float mn = fmaxf(m, mo);
      s = s * fexp2(m - mn) + so * fexp2(mo - mn);
      m = mn;
    }
    if (lane == 0) {
      float val = NEL2c * (m + flog2(s));       // -eps * LSE_e
      const int row = wrow0 + r;
      outp[row] = avg ? 0.5f * (oldp[row] + val) : val;
    }
  }
}

// loss = mean(f - px) + mean(g - py)
__global__ __launch_bounds__(256) void loss_kernel(
    const float* __restrict__ f,  const float* __restrict__ g,
    const float* __restrict__ px, const float* __restrict__ py,
    float* __restrict__ out)
{
  double acc = 0.0;
  for (int i = threadIdx.x; i < NP; i += 256)
    acc += (double)(f[i] - px[i]) + (double)(g[i] - py[i]);
  __shared__ double red[4];
#pragma unroll
  for (int off = 32; off; off >>= 1)
    acc += __shfl_xor(acc, off);
  const int lane = threadIdx.x & 63, wave = threadIdx.x >> 6;
  if (lane == 0) red[wave] = acc;
  __syncthreads();
  if (threadIdx.x == 0)
    out[0] = (float)((red[0] + red[1] + red[2] + red[3]) * (1.0 / NP));
}

extern "C" void kernel_launch(void* const* d_in, const int* in_sizes, int n_in,
                              void* d_out, int out_size, void* d_ws, size_t ws_size,
                              hipStream_t stream)
{
  const float* x = (const float*)d_in[0];
  const float* y = (const float*)d_in[1];
  float* out = (float*)d_out;
  float* ws  = (float*)d_ws;

  float4* X4 = (float4*)ws;              // NP float4
  float4* Y4 = (float4*)(ws + 4 * NP);   // NP float4
  float* A = ws + 8 * NP;                // f,g,px,py (current)
  float* B = A + 4 * NP;                 // f,g,px,py (next)

  hipLaunchKernelGGL(init_kernel, dim3((NP + 255) / 256), dim3(256), 0, stream,
                     x, y, X4, Y4, A);

  float* cur = A; float* nxt = B;
  for (int it = 0; it <= 32; ++it) {
    const int avg = (it < 32) ? 1 : 0;   // 32 averaged steps + 1 extrapolation
    hipLaunchKernelGGL(softmin_pass, dim3(4 * BPS), dim3(256), 0, stream,
                       X4, Y4,
                       cur, cur + NP, cur + 2*NP, cur + 3*NP,
                       nxt, nxt + NP, nxt + 2*NP, nxt + 3*NP, avg);
    float* t = cur; cur = nxt; nxt = t;
  }

  hipLaunchKernelGGL(loss_kernel, dim3(1), dim3(256), 0, stream,
                     cur, cur + NP, cur + 2*NP, cur + 3*NP, out);
}

// Round 4
// 2560.750 us; speedup vs baseline: 1.2616x; 1.2616x over previous
//
#include <hip/hip_runtime.h>
#include <math.h>

#ifndef __has_builtin
#define __has_builtin(x) 0
#endif

__device__ __forceinline__ float fexp2(float x) {
#if __has_builtin(__builtin_amdgcn_exp2f)
  return __builtin_amdgcn_exp2f(x);
#else
  return exp2f(x);
#endif
}
__device__ __forceinline__ float flog2(float x) {
#if __has_builtin(__builtin_amdgcn_logf)
  return __builtin_amdgcn_logf(x);
#else
  return log2f(x);
#endif
}
__device__ __forceinline__ float fsqrt_(float x) {
#if __has_builtin(__builtin_amdgcn_sqrtf)
  return __builtin_amdgcn_sqrtf(x);
#else
  return sqrtf(x);
#endif
}

constexpr int   NP    = 6144;
constexpr float LOG2E = 1.44269504088896340736f;
constexpr float EPS_F = 0.01f;
constexpr float KKc   = LOG2E / EPS_F;               // log2(e)/eps
constexpr float NKKc  = -KKc;
constexpr float LBc   = -8.72323127482750f;          // log(1/6144)
constexpr float HBc   = LBc * LOG2E;                 // log-weight, base-2
constexpr float NEL2c = -EPS_F * 0.693147180559945f; // -eps*ln(2)

constexpr int TILE = 1024;         // Q points staged per LDS tile
constexpr int NT   = NP / TILE;    // 6 tiles
constexpr int RPW  = 4;            // rows per wave (per lane)
constexpr int RPB  = 16;           // rows per block (4 waves)
constexpr int BPS  = NP / RPB;     // 384 blocks per subproblem

// Precompute P-form (x,y,z,|p|^2), Q-form (-2x,-2y,-2z,|p|^2); zero states.
__global__ __launch_bounds__(256) void init_kernel(
    const float* __restrict__ x, const float* __restrict__ y,
    float4* __restrict__ Xp, float4* __restrict__ Yp,
    float4* __restrict__ Xq, float4* __restrict__ Yq,
    float* __restrict__ st)
{
  int i = blockIdx.x * 256 + threadIdx.x;
  if (i < NP) {
    float a0 = x[3*i], a1 = x[3*i+1], a2 = x[3*i+2];
    float an = fmaf(a0, a0, fmaf(a1, a1, a2*a2));
    Xp[i] = make_float4(a0, a1, a2, an);
    Xq[i] = make_float4(-2.f*a0, -2.f*a1, -2.f*a2, an);
    float b0 = y[3*i], b1 = y[3*i+1], b2 = y[3*i+2];
    float bn = fmaf(b0, b0, fmaf(b1, b1, b2*b2));
    Yp[i] = make_float4(b0, b1, b2, bn);
    Yq[i] = make_float4(-2.f*b0, -2.f*b1, -2.f*b2, bn);
    st[i] = 0.f; st[i + NP] = 0.f; st[i + 2*NP] = 0.f; st[i + 3*NP] = 0.f;
  }
}

// One Sinkhorn step: 4 fused softmin passes (ft, gt, p_x, p_y).
__global__ __launch_bounds__(256, 6) void softmin_pass(
    const float4* __restrict__ Xp, const float4* __restrict__ Yp,
    const float4* __restrict__ Xq, const float4* __restrict__ Yq,
    const float* __restrict__ f_in,  const float* __restrict__ g_in,
    const float* __restrict__ px_in, const float* __restrict__ py_in,
    float* __restrict__ f_out,  float* __restrict__ g_out,
    float* __restrict__ px_out, float* __restrict__ py_out,
    int avg)
{
  __shared__ float4 sQ[TILE];
  __shared__ float  sH[TILE];

  const int bid   = blockIdx.x;
  const int sub   = bid / BPS;
  const int row0  = (bid - sub * BPS) * RPB;
  const int tid   = threadIdx.x;
  const int lane  = tid & 63;
  const int wave  = tid >> 6;
  const int wrow0 = row0 + wave * RPW;

  const float4* P4;  const float4* Q4;
  const float* hsrc; const float* oldp; float* outp;
  if (sub == 0)      { P4 = Xp; Q4 = Yq; hsrc = g_in;  oldp = f_in;  outp = f_out;  }
  else if (sub == 1) { P4 = Yp; Q4 = Xq; hsrc = f_in;  oldp = g_in;  outp = g_out;  }
  else if (sub == 2) { P4 = Xp; Q4 = Xq; hsrc = px_in; oldp = px_in; outp = px_out; }
  else               { P4 = Yp; Q4 = Yq; hsrc = py_in; oldp = py_in; outp = py_out; }

  float pxr[RPW], pyr[RPW], pzr[RPW], pwr[RPW];
  float mr[RPW], sr[RPW], m40[RPW];
#pragma unroll
  for (int r = 0; r < RPW; ++r) {
    float4 p = P4[wrow0 + r];
    pxr[r] = p.x; pyr[r] = p.y; pzr[r] = p.z; pwr[r] = p.w;
    mr[r] = -INFINITY; sr[r] = 0.f; m40[r] = -INFINITY;
  }

  for (int t = 0; t < NT; ++t) {
    __syncthreads();
#pragma unroll
    for (int v = tid; v < TILE; v += 256) {
      sQ[v] = Q4[t * TILE + v];
      sH[v] = fmaf(KKc, hsrc[t * TILE + v], HBc);  // (logw + state/eps)*log2e
    }
    __syncthreads();
#pragma unroll 4
    for (int k = lane; k < TILE; k += 64) {
      const float4 q  = sQ[k];
      const float  hh = sH[k];
#pragma unroll
      for (int r = 0; r < RPW; ++r) {
        // d2 = |p|^2 + |q|^2 - 2 p.q  (q pre-scaled by -2, |q|^2 folded into chain)
        float dot = fmaf(pxr[r], q.x, fmaf(pyr[r], q.y, fmaf(pzr[r], q.z, q.w)));
        float d2  = pwr[r] + dot;
        float c   = fsqrt_(fmaxf(d2, 1e-12f));
        float u   = fmaf(NKKc, c, hh);           // base-2 exponent
        // wave-uniform defer-max: rescale only if ANY lane exceeds its m+40
        if (__any(u > m40[r])) {
          float mn = fmaxf(mr[r], u);
          sr[r] *= fexp2(mr[r] - mn);
          mr[r]  = mn;
          m40[r] = mn + 40.f;
        }
        sr[r] += fexp2(u - mr[r]);
      }
    }
  }

  // combine per-lane partial (m, s) LSE states across the wave
#pragma unroll
  for (int r = 0; r < RPW; ++r) {
    float m = mr[r], s = sr[r];
#pragma unroll
    for (int off = 32; off; off >>= 1) {
      float mo = __shfl_xor(m, off);
      float so = __shfl_xor(s, off);
      float mn = fmaxf(m, mo);
      s = s * fexp2(m - mn) + so * fexp2(mo - mn);
      m = mn;
    }
    if (lane == 0) {
      float val = NEL2c * (m + flog2(s));        // -eps * LSE_e
      const int row = wrow0 + r;
      outp[row] = avg ? 0.5f * (oldp[row] + val) : val;
    }
  }
}

// loss = mean(f - px) + mean(g - py)
__global__ __launch_bounds__(256) void loss_kernel(
    const float* __restrict__ f,  const float* __restrict__ g,
    const float* __restrict__ px, const float* __restrict__ py,
    float* __restrict__ out)
{
  double acc = 0.0;
  for (int i = threadIdx.x; i < NP; i += 256)
    acc += (double)(f[i] - px[i]) + (double)(g[i] - py[i]);
  __shared__ double red[4];
#pragma unroll
  for (int off = 32; off; off >>= 1)
    acc += __shfl_xor(acc, off);
  const int lane = threadIdx.x & 63, wave = threadIdx.x >> 6;
  if (lane == 0) red[wave] = acc;
  __syncthreads();
  if (threadIdx.x == 0)
    out[0] = (float)((red[0] + red[1] + red[2] + red[3]) * (1.0 / NP));
}

extern "C" void kernel_launch(void* const* d_in, const int* in_sizes, int n_in,
                              void* d_out, int out_size, void* d_ws, size_t ws_size,
                              hipStream_t stream)
{
  const float* x = (const float*)d_in[0];
  const float* y = (const float*)d_in[1];
  float* out = (float*)d_out;
  float* ws  = (float*)d_ws;

  float4* Xp = (float4*)ws;                    // NP float4
  float4* Yp = (float4*)(ws + 4 * NP);
  float4* Xq = (float4*)(ws + 8 * NP);
  float4* Yq = (float4*)(ws + 12 * NP);
  float* A = ws + 16 * NP;                     // f,g,px,py (current)
  float* B = A + 4 * NP;                       // f,g,px,py (next)

  hipLaunchKernelGGL(init_kernel, dim3((NP + 255) / 256), dim3(256), 0, stream,
                     x, y, Xp, Yp, Xq, Yq, A);

  float* cur = A; float* nxt = B;
  for (int it = 0; it <= 32; ++it) {
    const int avg = (it < 32) ? 1 : 0;   // 32 averaged steps + 1 extrapolation
    hipLaunchKernelGGL(softmin_pass, dim3(4 * BPS), dim3(256), 0, stream,
                       Xp, Yp, Xq, Yq,
                       cur, cur + NP, cur + 2*NP, cur + 3*NP,
                       nxt, nxt + NP, nxt + 2*NP, nxt + 3*NP, avg);
    float* t = cur; cur = nxt; nxt = t;
  }

  hipLaunchKernelGGL(loss_kernel, dim3(1), dim3(256), 0, stream,
                     cur, cur + NP, cur + 2*NP, cur + 3*NP, out);
}

// Round 5
// 2384.738 us; speedup vs baseline: 1.3548x; 1.0738x over previous
//
#include <hip/hip_runtime.h>
#include <math.h>

#ifndef __has_builtin
#define __has_builtin(x) 0
#endif

__device__ __forceinline__ float fexp2(float x) {
#if __has_builtin(__builtin_amdgcn_exp2f)
  return __builtin_amdgcn_exp2f(x);
#else
  return exp2f(x);
#endif
}
__device__ __forceinline__ float flog2(float x) {
#if __has_builtin(__builtin_amdgcn_logf)
  return __builtin_amdgcn_logf(x);
#else
  return log2f(x);
#endif
}
__device__ __forceinline__ float fsqrt_(float x) {
#if __has_builtin(__builtin_amdgcn_sqrtf)
  return __builtin_amdgcn_sqrtf(x);
#else
  return sqrtf(x);
#endif
}

constexpr int   NP    = 6144;
constexpr float LOG2E = 1.44269504088896340736f;
constexpr float EPS_F = 0.01f;
constexpr float KKc   = LOG2E / EPS_F;               // log2(e)/eps
constexpr float NKKc  = -KKc;
constexpr float LBc   = -8.72323127482750f;          // log(1/6144)
constexpr float HBc   = LBc * LOG2E;                 // log-weight, base-2
constexpr float NEL2c = -EPS_F * 0.693147180559945f; // -eps*ln(2)

constexpr int RPW  = 8;            // rows per wave
constexpr int RPB  = 32;           // rows per block (4 waves)
constexpr int NRB  = NP / RPB;     // 192 row-blocks per subproblem
constexpr int NTL  = NP / 64;      // 96 column tiles of 64
constexpr int CELLS = 4096;        // 16^3 morton cells

// ---------------- sort / precompute (runs once per launch) ----------------
__device__ __forceinline__ unsigned cell_of(float v) {
  int c = (int)floorf((v + 4.0f) * 2.0f);        // cell edge 0.5 over [-4,4]
  return (unsigned)min(15, max(0, c));
}
__device__ __forceinline__ unsigned morton12(unsigned cx, unsigned cy, unsigned cz) {
  unsigned m = 0;
#pragma unroll
  for (int b = 0; b < 4; ++b)
    m |= (((cx >> b) & 1u) << (3 * b)) | (((cy >> b) & 1u) << (3 * b + 1)) |
         (((cz >> b) & 1u) << (3 * b + 2));
  return m;
}

// block 0 sorts X, block 1 sorts Y (morton counting sort), builds tile AABBs,
// zeroes half the state + hmax arrays each.
__global__ __launch_bounds__(1024) void sort_kernel(
    const float* __restrict__ xin, const float* __restrict__ yin,
    float4* __restrict__ Xp, float4* __restrict__ Xq,
    float4* __restrict__ Yp, float4* __restrict__ Yq,
    float4* __restrict__ XaLo, float4* __restrict__ XaHi,
    float4* __restrict__ YaLo, float4* __restrict__ YaHi,
    float* __restrict__ stA, float* __restrict__ hmaxA)
{
  __shared__ unsigned hist[CELLS];
  __shared__ unsigned offs[CELLS];
  __shared__ unsigned wsum[64];
  const int tid = threadIdx.x;
  const float* src = (blockIdx.x == 0) ? xin : yin;
  float4* Pp  = (blockIdx.x == 0) ? Xp : Yp;
  float4* Pq  = (blockIdx.x == 0) ? Xq : Yq;
  float4* aLo = (blockIdx.x == 0) ? XaLo : YaLo;
  float4* aHi = (blockIdx.x == 0) ? XaHi : YaHi;

  for (int i = tid; i < CELLS; i += 1024) { hist[i] = 0u; offs[i] = 0u; }
  // zero states & hmax (split between the two blocks)
  for (int i = tid; i < 2 * NP; i += 1024) stA[blockIdx.x * 2 * NP + i] = 0.f;
  for (int i = tid; i < 2 * NRB; i += 1024) hmaxA[blockIdx.x * 2 * NRB + i] = 0.f;
  __syncthreads();

  for (int i = tid; i < NP; i += 1024) {
    float a0 = src[3*i], a1 = src[3*i+1], a2 = src[3*i+2];
    unsigned m = morton12(cell_of(a0), cell_of(a1), cell_of(a2));
    atomicAdd(&hist[m], 1u);
  }
  __syncthreads();
  // exclusive scan of hist[4096]: 64 threads x 64 serial, then 1x64, add back
  if (tid < 64) {
    unsigned s = 0;
    for (int j = 0; j < 64; ++j) { unsigned v = hist[tid*64+j]; hist[tid*64+j] = s; s += v; }
    wsum[tid] = s;
  }
  __syncthreads();
  if (tid == 0) {
    unsigned s = 0;
    for (int j = 0; j < 64; ++j) { unsigned v = wsum[j]; wsum[j] = s; s += v; }
  }
  __syncthreads();
  if (tid < 64) {
    unsigned o = wsum[tid];
    for (int j = 0; j < 64; ++j) hist[tid*64+j] += o;
  }
  __syncthreads();
  // scatter
  for (int i = tid; i < NP; i += 1024) {
    float a0 = src[3*i], a1 = src[3*i+1], a2 = src[3*i+2];
    unsigned m = morton12(cell_of(a0), cell_of(a1), cell_of(a2));
    unsigned dst = hist[m] + atomicAdd(&offs[m], 1u);
    float an = fmaf(a0, a0, fmaf(a1, a1, a2 * a2));
    Pp[dst] = make_float4(a0, a1, a2, an);
    Pq[dst] = make_float4(-2.f*a0, -2.f*a1, -2.f*a2, an);
  }
  __syncthreads();
  // tile AABBs: 16 waves x 6 tiles of 64 sorted points
  const int wave = tid >> 6, lane = tid & 63;
  for (int t = wave; t < NTL; t += 16) {
    float4 p = Pp[t * 64 + lane];
    float lx = p.x, ly = p.y, lz = p.z, hx = p.x, hy = p.y, hz = p.z;
#pragma unroll
    for (int off = 32; off; off >>= 1) {
      lx = fminf(lx, __shfl_xor(lx, off)); hx = fmaxf(hx, __shfl_xor(hx, off));
      ly = fminf(ly, __shfl_xor(ly, off)); hy = fmaxf(hy, __shfl_xor(hy, off));
      lz = fminf(lz, __shfl_xor(lz, off)); hz = fmaxf(hz, __shfl_xor(hz, off));
    }
    if (lane == 0) {
      aLo[t] = make_float4(lx, ly, lz, 0.f);
      aHi[t] = make_float4(hx, hy, hz, 0.f);
    }
  }
}

// ---------------- fused culled softmin pass ----------------
// grid = 4 subs x 192 row-blocks (sub = bid&3). Each wave owns 8 sorted rows,
// builds a per-wave 96-bit tile mask from conservative AABB bounds, and only
// evaluates surviving tiles (lane = column within tile, no LDS staging).
__global__ __launch_bounds__(256, 4) void softmin_pass(
    const float4* __restrict__ Xp, const float4* __restrict__ Yp,
    const float4* __restrict__ Xq, const float4* __restrict__ Yq,
    const float4* __restrict__ XaLo, const float4* __restrict__ XaHi,
    const float4* __restrict__ YaLo, const float4* __restrict__ YaHi,
    const float* __restrict__ stIn, const float* __restrict__ hmaxIn,
    float* __restrict__ stOut, float* __restrict__ hmaxOut, int avg)
{
  const int bid  = blockIdx.x;
  const int sub  = bid & 3;
  const int rb   = bid >> 2;
  const int tid  = threadIdx.x;
  const int lane = tid & 63;
  const int wave = tid >> 6;
  const int wrow0 = rb * RPB + wave * RPW;

  const float4 *P4, *Q4, *aLo, *aHi;
  const float *hsrc, *hpair, *oldp; float* outp;
  if (sub == 0) {        // f <- softmin over Y cols, h from g
    P4 = Xp; Q4 = Yq; aLo = YaLo; aHi = YaHi;
    hsrc = stIn + NP;     hpair = hmaxIn + NRB;     oldp = stIn;          outp = stOut;
  } else if (sub == 1) { // g <- softmin over X cols, h from f
    P4 = Yp; Q4 = Xq; aLo = XaLo; aHi = XaHi;
    hsrc = stIn;          hpair = hmaxIn;           oldp = stIn + NP;     outp = stOut + NP;
  } else if (sub == 2) { // px (xx)
    P4 = Xp; Q4 = Xq; aLo = XaLo; aHi = XaHi;
    hsrc = stIn + 2*NP;   hpair = hmaxIn + 2*NRB;   oldp = stIn + 2*NP;   outp = stOut + 2*NP;
  } else {               // py (yy)
    P4 = Yp; Q4 = Yq; aLo = YaLo; aHi = YaHi;
    hsrc = stIn + 3*NP;   hpair = hmaxIn + 3*NRB;   oldp = stIn + 3*NP;   outp = stOut + 3*NP;
  }

  // load the wave's 8 rows (wave-uniform) + row AABB
  float pxr[RPW], pyr[RPW], pzr[RPW], pwr[RPW], mr[RPW], sr[RPW], m40r[RPW];
  float rlx, rly, rlz, rhx, rhy, rhz;
#pragma unroll
  for (int r = 0; r < RPW; ++r) {
    float4 p = P4[wrow0 + r];
    pxr[r] = p.x; pyr[r] = p.y; pzr[r] = p.z; pwr[r] = p.w;
    if (r == 0) { rlx = rhx = p.x; rly = rhy = p.y; rlz = rhz = p.z; }
    else {
      rlx = fminf(rlx, p.x); rhx = fmaxf(rhx, p.x);
      rly = fminf(rly, p.y); rhy = fmaxf(rhy, p.y);
      rlz = fminf(rlz, p.z); rhz = fmaxf(rhz, p.z);
    }
  }

  // per-wave tile bounds: lanes evaluate tiles (round A: 0-63, round B: 64-95)
  float b0, b1, uc0, uc1;
  {
    auto tile_bounds = [&](int t, float& b, float& uc) {
      float4 lo = aLo[t], hi = aHi[t];
      float gx = fmaxf(fmaxf(lo.x - rhx, rlx - hi.x), 0.f);
      float gy = fmaxf(fmaxf(lo.y - rhy, rly - hi.y), 0.f);
      float gz = fmaxf(fmaxf(lo.z - rhz, rlz - hi.z), 0.f);
      float dmin = fsqrt_(fmaf(gx, gx, fmaf(gy, gy, gz * gz)));
      float fx = fmaxf(hi.x - rlx, rhx - lo.x);
      float fy = fmaxf(hi.y - rly, rhy - lo.y);
      float fz = fmaxf(hi.z - rlz, rhz - lo.z);
      float dmax = fsqrt_(fmaf(fx, fx, fmaf(fy, fy, fz * fz)));
      float hraw = fmaxf(hpair[2 * t], hpair[2 * t + 1]);
      float hh = fmaf(KKc, hraw, HBc);
      b  = fmaf(NKKc, dmin, hh);   // upper bound of any term in tile
      uc = fmaf(NKKc, dmax, hh);   // achievable lower bound for every row
    };
    tile_bounds(lane, b0, uc0);
    int tB = (lane < 32) ? (64 + lane) : 95;
    tile_bounds(tB, b1, uc1);
    if (lane >= 32) { b1 = -INFINITY; uc1 = -INFINITY; }
  }
  float ulb = fmaxf(uc0, uc1);
#pragma unroll
  for (int off = 32; off; off >>= 1) ulb = fmaxf(ulb, __shfl_xor(ulb, off));
  const float thr = ulb - 40.f;
  unsigned long long mA = __ballot(b0 >= thr);
  unsigned long long mB = __ballot(b1 >= thr);   // lanes>=32 contribute 0

#pragma unroll
  for (int r = 0; r < RPW; ++r) { mr[r] = ulb; sr[r] = 0.f; m40r[r] = ulb + 40.f; }

  auto proc = [&](int t) {
    int j = t * 64 + lane;
    float4 q = Q4[j];
    float hh = fmaf(KKc, hsrc[j], HBc);
#pragma unroll
    for (int r = 0; r < RPW; ++r) {
      float dot = fmaf(pxr[r], q.x, fmaf(pyr[r], q.y, fmaf(pzr[r], q.z, q.w)));
      float d2  = pwr[r] + dot;
      float c   = fsqrt_(fmaxf(d2, 1e-12f));
      float u   = fmaf(NKKc, c, hh);
      if (__any(u > m40r[r])) {
        float mn = fmaxf(mr[r], u);
        sr[r] *= fexp2(mr[r] - mn);
        mr[r] = mn; m40r[r] = mn + 40.f;
      }
      sr[r] += fexp2(u - mr[r]);
    }
  };
  while (mA) { int t = __ffsll(mA) - 1;  mA &= mA - 1; proc(t); }
  while (mB) { int t = 63 + __ffsll(mB); mB &= mB - 1; proc(t); }

  // merge per-lane LSE states; write outputs; per-block max for next pass
  __shared__ float wmaxLds[4];
  float wmax = -INFINITY;
#pragma unroll
  for (int r = 0; r < RPW; ++r) {
    float m = mr[r], s = sr[r];
#pragma unroll
    for (int off = 32; off; off >>= 1) {
      float mo = __shfl_xor(m, off);
      float so = __shfl_xor(s, off);
      float mn = fmaxf(m, mo);
      s = s * fexp2(m - mn) + so * fexp2(mo - mn);
      m = mn;
    }
    float val = NEL2c * (m + flog2(s));
    const int row = wrow0 + r;
    float wv = avg ? 0.5f * (oldp[row] + val) : val;
    if (lane == 0) outp[row] = wv;
    wmax = fmaxf(wmax, wv);
  }
  if (lane == 0) wmaxLds[wave] = wmax;
  __syncthreads();
  if (tid == 0)
    hmaxOut[sub * NRB + rb] =
        fmaxf(fmaxf(wmaxLds[0], wmaxLds[1]), fmaxf(wmaxLds[2], wmaxLds[3]));
}

// loss = mean(f - px) + mean(g - py)
__global__ __launch_bounds__(256) void loss_kernel(
    const float* __restrict__ st, float* __restrict__ out)
{
  double acc = 0.0;
  for (int i = threadIdx.x; i < NP; i += 256)
    acc += (double)(st[i] - st[i + 2*NP]) + (double)(st[i + NP] - st[i + 3*NP]);
  __shared__ double red[4];
#pragma unroll
  for (int off = 32; off; off >>= 1) acc += __shfl_xor(acc, off);
  const int lane = threadIdx.x & 63, wave = threadIdx.x >> 6;
  if (lane == 0) red[wave] = acc;
  __syncthreads();
  if (threadIdx.x == 0)
    out[0] = (float)((red[0] + red[1] + red[2] + red[3]) * (1.0 / NP));
}

extern "C" void kernel_launch(void* const* d_in, const int* in_sizes, int n_in,
                              void* d_out, int out_size, void* d_ws, size_t ws_size,
                              hipStream_t stream)
{
  const float* x = (const float*)d_in[0];
  const float* y = (const float*)d_in[1];
  float* out = (float*)d_out;
  float* ws  = (float*)d_ws;

  float4* Xp = (float4*)ws;                    // NP float4 each
  float4* Xq = (float4*)(ws + 4 * NP);
  float4* Yp = (float4*)(ws + 8 * NP);
  float4* Yq = (float4*)(ws + 12 * NP);
  float*  p  = ws + 16 * NP;
  float4* XaLo = (float4*)p; p += 4 * NTL;
  float4* XaHi = (float4*)p; p += 4 * NTL;
  float4* YaLo = (float4*)p; p += 4 * NTL;
  float4* YaHi = (float4*)p; p += 4 * NTL;
  float* stA = p;            p += 4 * NP;
  float* stB = p;            p += 4 * NP;
  float* hmA = p;            p += 4 * NRB;
  float* hmB = p;

  hipLaunchKernelGGL(sort_kernel, dim3(2), dim3(1024), 0, stream,
                     x, y, Xp, Xq, Yp, Yq, XaLo, XaHi, YaLo, YaHi, stA, hmA);

  float* cur = stA; float* nxt = stB;
  float* hmCur = hmA; float* hmNxt = hmB;
  for (int it = 0; it <= 32; ++it) {
    const int avg = (it < 32) ? 1 : 0;   // 32 averaged steps + 1 extrapolation
    hipLaunchKernelGGL(softmin_pass, dim3(4 * NRB), dim3(256), 0, stream,
                       Xp, Yp, Xq, Yq, XaLo, XaHi, YaLo, YaHi,
                       cur, hmCur, nxt, hmNxt, avg);
    float* t = cur; cur = nxt; nxt = t;
    t = hmCur; hmCur = hmNxt; hmNxt = t;
  }

  hipLaunchKernelGGL(loss_kernel, dim3(1), dim3(256), 0, stream, cur, out);
}